// Round 2
// baseline (359.011 us; speedup 1.0000x reference)
//
#include <hip/hip_runtime.h>
#include <hip/hip_bf16.h>

// PrimaryCaps fused 1x1 convs -> per-n GEMM: Out[544,1024] = W[544,512] * X_n[512,1024]
// R4: occupancy + pipeline-depth fix on the R3 traffic-minimal structure.
//  - TM 64->32: per wave 144 rows x 32 cols -> acc 9x2 f32x4 = 72 VGPR (R3: 144).
//    Total regs ~120 -> 4 waves/SIMD -> 16 waves/CU (4 blocks/CU), vs R3's 7 waves.
//  - 2-deep X prefetch: tile k+2 issued while computing k / storing k+1 -> a full
//    iteration (~500+ cy) of latency budget per HBM load, vs R3's intra-iter 1-deep.
//  - 4 phase-staggered blocks/CU overlap epilogue store bursts with other blocks' loads.
//  - x still read from HBM exactly once (all 544 rows per block); W bf16 (576x512,
//    590 KB, prep_w) streamed from L2 as A-fragments, no A LDS/barriers.
// LDS: X tile [32 m][64 k] bf16 dbuf = 8 KB, slot ^= (m&7) swizzle -> conflict-free b128.

typedef __attribute__((ext_vector_type(8))) short short8;
typedef __attribute__((ext_vector_type(4))) float f32x4;

#define A_CH   512
#define HW     1024
#define N_B    64
#define O_POSE 512
#define O_ACT  32
#define O_TOT  544
#define O_PAD  576            // 4 waves * 9 frags * 16 rows
#define TM     32
#define BK     64
#define NIT    (A_CH / BK)    // 8
#define NOF    9              // 16-row o-frags per wave

__device__ __forceinline__ unsigned pk(float lo, float hi) {
    __hip_bfloat162 h = __float22bfloat162_rn(make_float2(lo, hi));
    return *reinterpret_cast<unsigned*>(&h);
}

// ---- pre-kernel: W fp32 (512 pose rows ++ 32 act rows) -> bf16 [576][512] in ws,
// rows 544..575 zeroed. Fully rewritten every launch (re-poison safe).
__global__ __launch_bounds__(256) void prep_w(const float* __restrict__ Wp,
                                              const float* __restrict__ Wa,
                                              unsigned short* __restrict__ Wb) {
    const int r = blockIdx.x;
    const int c = threadIdx.x * 2;
    float2 v = make_float2(0.f, 0.f);
    if (r < O_POSE)     v = *(const float2*)(Wp + (size_t)r * A_CH + c);
    else if (r < O_TOT) v = *(const float2*)(Wa + (size_t)(r - O_POSE) * A_CH + c);
    __hip_bfloat162 h = __float22bfloat162_rn(v);
    *(unsigned*)(Wb + (size_t)r * A_CH + c) = *reinterpret_cast<unsigned*>(&h);
}

__global__ __launch_bounds__(256, 4) void caps_gemm(
    const float* __restrict__ x,            // [64,512,32,32] fp32
    const unsigned short* __restrict__ Wb,  // [576,512] bf16 (padded)
    const float* __restrict__ bp,           // [512]
    const float* __restrict__ ba,           // [32]
    float* __restrict__ out)                // poses [64,512,1024] ++ act [64,32,1024]
{
    __shared__ __align__(16) short lds[2][TM * BK];   // 2 x 4 KB

    const int tid = threadIdx.x;
    const int m0  = blockIdx.x * TM;
    const int n   = blockIdx.y;

    const float* xn = x + (size_t)n * A_CH * HW + m0;

    // ---- X staging: thread t -> m = t&31, k-octet g = t>>5 (0..7).
    // 8 dword loads per tile; each wave instr = 2 k-rows x 128 B contiguous.
    const int sm = tid & 31;
    const int sg = tid >> 5;
    const float* sbase = xn + (size_t)sg * 8 * HW + sm;
    // one b128 LDS write per tile: row sm, slot sg, swizzled
    const int wr = sm * BK + ((sg ^ (sm & 7)) << 3);

    float xr[2][8];                          // 2-deep prefetch register banks
    auto load_x = [&](int it, int bank) {
#pragma unroll
        for (int j = 0; j < 8; ++j)
            xr[bank][j] = sbase[(size_t)(it * BK + j) * HW];
    };
    auto store_x = [&](int bank, int buf) {
        short8 v;
#pragma unroll
        for (int j = 0; j < 4; ++j)
            ((unsigned*)&v)[j] = pk(xr[bank][2 * j], xr[bank][2 * j + 1]);
        *(short8*)&lds[buf][wr] = v;
    };

    // ---- wave w owns rows [w*144, w*144+144) x all 32 cols
    const int lane = tid & 63;
    const int w    = tid >> 6;
    const int l16  = lane & 15;
    const int g    = lane >> 4;

    const unsigned short* wlane = Wb + (size_t)(w * 144 + l16) * A_CH + g * 8;
    const int bswz = l16 & 7;                // (fm*16+l16)&7 == l16&7

    f32x4 acc[NOF][2] = {};                  // 72 VGPRs

    load_x(0, 0);
    load_x(1, 1);
    store_x(0, 0);
    __syncthreads();

    for (int it = 0; it < NIT; ++it) {
        const int cur = it & 1;
        if (it + 2 < NIT) load_x(it + 2, it & 1);   // bank (it&1) was stored last iter
#pragma unroll
        for (int ks = 0; ks < 2; ++ks) {
            short8 bF[2];
#pragma unroll
            for (int fm = 0; fm < 2; ++fm)
                bF[fm] = *(const short8*)&lds[cur][(fm * 16 + l16) * BK +
                                                   (((ks * 4 + g) ^ bswz) << 3)];
#pragma unroll
            for (int of = 0; of < NOF; ++of) {
                short8 aF = *(const short8*)(wlane + (size_t)of * 16 * A_CH +
                                             it * BK + ks * 32);
#pragma unroll
                for (int fm = 0; fm < 2; ++fm)
                    acc[of][fm] = __builtin_amdgcn_mfma_f32_16x16x32_bf16(
                        aF, bF[fm], acc[of][fm], 0, 0, 0);
            }
        }
        if (it + 1 < NIT) store_x((it + 1) & 1, cur ^ 1);
        __syncthreads();   // single barrier per k-step (dbuf makes it safe)
    }

    // ---- epilogue: C/D layout col = lane&15, row = (lane>>4)*4 + reg
    float* actOut = out + (size_t)N_B * O_POSE * HW;
    const size_t poseN = (size_t)n * O_POSE * HW;
    const size_t actN  = (size_t)n * O_ACT * HW;
    const int ob = w * 144;
#pragma unroll
    for (int of = 0; of < NOF; ++of) {
#pragma unroll
        for (int i = 0; i < 4; ++i) {
            const int R = ob + of * 16 + g * 4 + i;
            if (R >= O_TOT) continue;              // padded rows 544..575
            if (R < O_POSE) {
                const float bias = bp[R];
#pragma unroll
                for (int fm = 0; fm < 2; ++fm) {
                    const int cc = m0 + fm * 16 + l16;
                    __builtin_nontemporal_store(acc[of][fm][i] + bias,
                                                &out[poseN + (size_t)R * HW + cc]);
                }
            } else {
                const float bias = ba[R - O_POSE];
#pragma unroll
                for (int fm = 0; fm < 2; ++fm) {
                    const int cc = m0 + fm * 16 + l16;
                    const float v = acc[of][fm][i] + bias;
                    __builtin_nontemporal_store(1.0f / (1.0f + __expf(-v)),
                                                &actOut[actN + (size_t)(R - O_POSE) * HW + cc]);
                }
            }
        }
    }
}

extern "C" void kernel_launch(void* const* d_in, const int* in_sizes, int n_in,
                              void* d_out, int out_size, void* d_ws, size_t ws_size,
                              hipStream_t stream) {
    (void)in_sizes; (void)n_in; (void)out_size; (void)ws_size;
    const float* x  = (const float*)d_in[0];
    const float* Wp = (const float*)d_in[1];
    const float* bp = (const float*)d_in[2];
    const float* Wa = (const float*)d_in[3];
    const float* ba = (const float*)d_in[4];
    unsigned short* Wb = (unsigned short*)d_ws;   // needs 576*512*2 = 589,824 B

    prep_w<<<dim3(O_PAD), dim3(256), 0, stream>>>(Wp, Wa, Wb);
    caps_gemm<<<dim3(HW / TM, N_B), dim3(256), 0, stream>>>(x, Wb, bp, ba, (float*)d_out);
}

// Round 3
// 296.429 us; speedup vs baseline: 1.2111x; 1.2111x over previous
//
#include <hip/hip_runtime.h>
#include <hip/hip_bf16.h>

// PrimaryCaps fused 1x1 convs -> per-n GEMM: Out[544,1024] = W[544,512] * X_n[512,1024]
// R5: R2's verified tile machinery + the latency fixes R2 lacked.
//  - Root cause of R2's 2.45 TB/s (39% of achievable): __syncthreads emits
//    s_waitcnt vmcnt(0) -> every k-step drains the just-issued prefetch (~800 cy
//    exposed). Fix: counted vmcnt (never 0 mid-loop) + raw s_barrier, 2-deep prefetch.
//  - A (W) pre-converted to bf16 [640][512] by prep_w; staged via ONE 16B
//    global_load_lds per thread per iter, source pre-swizzled so the LDS layout
//    matches R2's conflict-free frag-read swizzle. No A pack VALU, half the A bytes.
//  - Tile 128x128, 512 thr: per-wave acc = 32 AGPR, X regs 2x8 -> ~90 unified regs,
//    4 waves/SIMD, 2 blocks/CU. A triple-buffered (2-ahead glds never hits readers),
//    X LDS double-buffered bf16.
//  - Grid 2560 linear, XCD-grouped: the 5 o-blocks sharing an X stripe -> same XCD,
//    adjacent dispatch -> X L2 hits instead of L3 re-reads.
// Pipeline per iter: issue batch(it+2) [1 glds + 8 X dwords]; frags+MFMA on tile it;
// s_waitcnt vmcnt(9) (retires batch it+1); pack X(it+1); lgkmcnt(0)+s_barrier (raw).

typedef __attribute__((ext_vector_type(8))) short short8;
typedef __attribute__((ext_vector_type(4))) float f32x4;

#define A_CH   512
#define HW     1024
#define N_B    64
#define O_POSE 512
#define O_ACT  32
#define O_TOT  544
#define O_PAD  640            // 5 o-tiles * 128
#define TO     128
#define TM     128
#define BK     32
#define NIT    (A_CH / BK)    // 16

__device__ __forceinline__ unsigned pk(float lo, float hi) {
    __hip_bfloat162 h = __float22bfloat162_rn(make_float2(lo, hi));
    return *reinterpret_cast<unsigned*>(&h);
}

__device__ __forceinline__ void glds16(const void* g, void* l) {
    __builtin_amdgcn_global_load_lds(
        (const __attribute__((address_space(1))) unsigned*)g,
        (__attribute__((address_space(3))) unsigned*)l, 16, 0, 0);
}

// ---- pre-kernel: W fp32 (512 pose ++ 32 act rows) -> bf16 [640][512] in ws,
// rows 544..639 zeroed. Fully rewritten every launch (re-poison safe).
__global__ __launch_bounds__(256) void prep_w(const float* __restrict__ Wp,
                                              const float* __restrict__ Wa,
                                              unsigned short* __restrict__ Wb) {
    const int r = blockIdx.x;
    const int c = threadIdx.x * 2;
    float2 v = make_float2(0.f, 0.f);
    if (r < O_POSE)     v = *(const float2*)(Wp + (size_t)r * A_CH + c);
    else if (r < O_TOT) v = *(const float2*)(Wa + (size_t)(r - O_POSE) * A_CH + c);
    __hip_bfloat162 h = __float22bfloat162_rn(v);
    *(unsigned*)(Wb + (size_t)r * A_CH + c) = *reinterpret_cast<unsigned*>(&h);
}

__global__ __launch_bounds__(512, 4) void caps_gemm(
    const float* __restrict__ x,            // [64,512,32,32] fp32
    const unsigned short* __restrict__ Wb,  // [640,512] bf16 (padded)
    const float* __restrict__ bp,           // [512]
    const float* __restrict__ ba,           // [32]
    float* __restrict__ out)                // poses [64,512,1024] ++ act [64,32,1024]
{
    __shared__ __align__(16) short ldsA[3][TO * BK];   // 3 x 8 KB (triple buffer)
    __shared__ __align__(16) short ldsB[2][TM * BK];   // 2 x 8 KB (double buffer)

    const int tid = threadIdx.x;

    // ---- XCD-grouped decode: xcd = lin&7; 5 o-blocks of one (m,n) are adjacent
    // slots on the same XCD -> X stripe fetched once to that XCD's L2.
    const int lin  = blockIdx.x;
    const int xcd  = lin & 7;
    const int slot = lin >> 3;              // 0..319 per XCD
    const int ob   = slot % 5;
    const int mnid = (slot / 5) * 8 + xcd;  // 0..511
    const int m0   = (mnid & 7) * TM;
    const int n    = mnid >> 3;
    const int o0   = ob * TO;

    // ---- A staging: dest linear tid*16B -> row rA=tid>>2, slot sA=tid&3.
    // Source pre-swizzled: k-octet = sA ^ ((rA>>1)&3)  (matches frag-read swizzle).
    const unsigned short* asrc =
        Wb + (size_t)(o0 + (tid >> 2)) * A_CH + (((tid & 3) ^ ((tid >> 3) & 3)) * 8);

    // ---- X staging: m = tid&127, k-octet kg = tid>>7. 8 dword loads per tile
    // (each wave instr = 64 consecutive m at one k = 256B). One b128 LDS write.
    const int sm = tid & 127;
    const int kg = tid >> 7;
    const float* sbase = x + (size_t)n * A_CH * HW + m0 + sm + (size_t)(kg * 8) * HW;
    const int xwr = sm * BK + ((kg ^ ((sm >> 1) & 3)) * 8);

    float xr[2][8];                          // 2-deep prefetch banks (static after unroll)

    const int lane = tid & 63;
    const int w    = tid >> 6;
    const int wo   = (w >> 2) * 64;          // wave row base   (2 x 64)
    const int wm   = (w & 3) * 32;           // wave col base   (4 x 32)
    const int l16  = lane & 15;
    const int g    = lane >> 4;

    f32x4 acc[4][2] = {};                    // 32 AGPR

    // ---- prologue: batches 0 and 1 (9 VMEM ops each), stage X(0), barrier
    glds16(asrc, &ldsA[0][tid * 8]);
#pragma unroll
    for (int j = 0; j < 8; ++j) xr[0][j] = sbase[(size_t)j * HW];
    asm volatile("" ::: "memory");           // keep batch0 | batch1 issue order
    glds16(asrc + BK, &ldsA[1][tid * 8]);
#pragma unroll
    for (int j = 0; j < 8; ++j) xr[1][j] = sbase[(size_t)(BK + j) * HW];

    asm volatile("s_waitcnt vmcnt(9)" ::: "memory");   // batch0 (A0 + X0) retired
    {
        short8 v;
#pragma unroll
        for (int j = 0; j < 4; ++j)
            ((unsigned*)&v)[j] = pk(xr[0][2 * j], xr[0][2 * j + 1]);
        *(short8*)&ldsB[0][xwr] = v;
    }
    asm volatile("s_waitcnt lgkmcnt(0)\n\ts_barrier" ::: "memory");

#pragma unroll
    for (int it = 0; it < NIT; ++it) {
        // a. issue batch(it+2): 1 glds (-> A buf (it+2)%3, never the one being read)
        //    + 8 X dwords into bank it&1 (held tile it, already packed).
        if (it + 2 < NIT) {
            glds16(asrc + (it + 2) * BK, &ldsA[(it + 2) % 3][tid * 8]);
#pragma unroll
            for (int j = 0; j < 8; ++j)
                xr[it & 1][j] = sbase[(size_t)((it + 2) * BK + j) * HW];
        }
        // b. frag reads, tile it
        short8 aF[4], bF[2];
#pragma unroll
        for (int f = 0; f < 4; ++f) {
            const int r = wo + f * 16 + l16;
            aF[f] = *(const short8*)&ldsA[it % 3][r * BK + ((g ^ ((r >> 1) & 3)) * 8)];
        }
#pragma unroll
        for (int f = 0; f < 2; ++f) {
            const int c = wm + f * 16 + l16;
            bF[f] = *(const short8*)&ldsB[it & 1][c * BK + ((g ^ ((c >> 1) & 3)) * 8)];
        }
        // c. MFMA
#pragma unroll
        for (int fo = 0; fo < 4; ++fo)
#pragma unroll
            for (int fm = 0; fm < 2; ++fm)
                acc[fo][fm] = __builtin_amdgcn_mfma_f32_16x16x32_bf16(
                    aF[fo], bF[fm], acc[fo][fm], 0, 0, 0);
        // d. counted wait: retire batch(it+1) (A(it+1) glds + X(it+1) regs),
        //    leave batch(it+2)'s 9 ops in flight. Then pack/write X(it+1).
        if (it + 1 < NIT) {
            if (it + 2 < NIT)
                asm volatile("s_waitcnt vmcnt(9)" ::: "memory");
            else
                asm volatile("s_waitcnt vmcnt(0)" ::: "memory");
            short8 v;
#pragma unroll
            for (int j = 0; j < 4; ++j)
                ((unsigned*)&v)[j] = pk(xr[(it + 1) & 1][2 * j], xr[(it + 1) & 1][2 * j + 1]);
            *(short8*)&ldsB[(it + 1) & 1][xwr] = v;
            // e. raw barrier: lgkmcnt(0) only -- NO vmcnt drain (the whole point)
            asm volatile("s_waitcnt lgkmcnt(0)\n\ts_barrier" ::: "memory");
        }
    }

    // ---- epilogue: C/D layout col = lane&15, row = (lane>>4)*4 + reg
    float* actOut = out + (size_t)N_B * O_POSE * HW;
    const size_t poseN = (size_t)n * O_POSE * HW;
    const size_t actN  = (size_t)n * O_ACT * HW;
#pragma unroll
    for (int fo = 0; fo < 4; ++fo) {
#pragma unroll
        for (int i = 0; i < 4; ++i) {
            const int R = o0 + wo + fo * 16 + g * 4 + i;
            if (R >= O_TOT) continue;              // padded rows 544..639
            if (R < O_POSE) {
                const float bias = bp[R];
#pragma unroll
                for (int fm = 0; fm < 2; ++fm) {
                    const int cc = m0 + wm + fm * 16 + l16;
                    __builtin_nontemporal_store(acc[fo][fm][i] + bias,
                                                &out[poseN + (size_t)R * HW + cc]);
                }
            } else {
                const float bias = ba[R - O_POSE];
#pragma unroll
                for (int fm = 0; fm < 2; ++fm) {
                    const int cc = m0 + wm + fm * 16 + l16;
                    const float v = acc[fo][fm][i] + bias;
                    __builtin_nontemporal_store(1.0f / (1.0f + __expf(-v)),
                                                &actOut[actN + (size_t)(R - O_POSE) * HW + cc]);
                }
            }
        }
    }
}

extern "C" void kernel_launch(void* const* d_in, const int* in_sizes, int n_in,
                              void* d_out, int out_size, void* d_ws, size_t ws_size,
                              hipStream_t stream) {
    (void)in_sizes; (void)n_in; (void)out_size; (void)ws_size;
    const float* x  = (const float*)d_in[0];
    const float* Wp = (const float*)d_in[1];
    const float* bp = (const float*)d_in[2];
    const float* Wa = (const float*)d_in[3];
    const float* ba = (const float*)d_in[4];
    unsigned short* Wb = (unsigned short*)d_ws;   // needs 640*512*2 = 655,360 B

    prep_w<<<dim3(O_PAD), dim3(256), 0, stream>>>(Wp, Wa, Wb);
    // 8 m-tiles * 5 o-tiles * 64 n = 2560 blocks, XCD-grouped decode in-kernel
    caps_gemm<<<dim3(8 * 5 * N_B), dim3(512), 0, stream>>>(x, Wb, bp, ba, (float*)d_out);
}